// Round 1
// baseline (922.466 us; speedup 1.0000x reference)
//
#include <hip/hip_runtime.h>
#include <math.h>

#define NS 131072
#define NFR 128
#define CPDIM 16
#define WIN 1024
#define NVOICE 8
#define NBLK 3
#define NCP 512
#define NVERB 8
#define NEV 64
#define FFTN 2048
#define FFT_LOG2 11
#define NBINS 1025

struct EvParams {
  int vidx, cpidx, ridx;
  float vm0, vm1, amp;
  float mixw0, mixw1, mixw2;
  unsigned int maxslot;
  int pad[6];
}; // 64 bytes

// ============================== FFT helpers ==============================
__device__ __forceinline__ void fill_tw(float* twr, float* twi, int tid) {
  for (int k = tid; k < FFTN / 2; k += 256) {
    float ang = (float)k * (-6.283185307179586f / (float)FFTN);
    float s, c;
    sincosf(ang, &s, &c);
    twr[k] = c;
    twi[k] = s;
  }
}

// in-place radix-2 DIT, input must be bit-reversed, output natural order
__device__ __forceinline__ void fft_stages(float* re, float* im,
                                           const float* twr, const float* twi,
                                           int tid, bool inverse) {
  for (int s = 1; s <= FFT_LOG2; ++s) {
    const int half = 1 << (s - 1);
    const int tstep = FFTN >> s;
    for (int k = tid; k < FFTN / 2; k += 256) {
      int j = k & (half - 1);
      int i0 = ((k ^ j) << 1) | j;
      int i1 = i0 + half;
      float wr = twr[j * tstep];
      float wi = twi[j * tstep];
      if (inverse) wi = -wi;
      float xr = re[i1], xi = im[i1];
      float tr = wr * xr - wi * xi;
      float ti = wr * xi + wi * xr;
      float ur = re[i0], ui = im[i0];
      re[i0] = ur + tr; im[i0] = ui + ti;
      re[i1] = ur - tr; im[i1] = ui - ti;
    }
    __syncthreads();
  }
}

// ============================== K0: per-event params ==============================
__global__ void k0_params(const float* __restrict__ voice, const float* __restrict__ cpc,
                          const float* __restrict__ amps, const float* __restrict__ roomc,
                          const float* __restrict__ roomm, const float* __restrict__ mix,
                          EvParams* __restrict__ P) {
  int e = blockIdx.x;
  int tid = threadIdx.x; // 64 threads
  __shared__ float bvals[64];
  __shared__ int bidx[64];

  if (tid == 0) {
    const float* v = voice + e * NVOICE;
    int vi = 0; float bv = v[0];
    for (int i = 1; i < NVOICE; ++i) if (v[i] > bv) { bv = v[i]; vi = i; }
    P[e].vidx = vi;

    const float* r = roomc + e * NVERB;
    int ri = 0; float br = r[0];
    for (int i = 1; i < NVERB; ++i) if (r[i] > br) { br = r[i]; ri = i; }
    P[e].ridx = ri;

    float m0 = roomm[e * 2 + 0], m1 = roomm[e * 2 + 1];
    float mx = fmaxf(m0, m1);
    float e0 = expf(m0 - mx), e1 = expf(m1 - mx);
    float inv = 1.0f / (e0 + e1);
    P[e].vm0 = e0 * inv;
    P[e].vm1 = e1 * inv;
    P[e].amp = fabsf(amps[e]);

    const float* mm = mix + vi * NBLK;
    float mmx = fmaxf(fmaxf(mm[0], mm[1]), mm[2]);
    float w0 = expf(mm[0] - mmx), w1 = expf(mm[1] - mmx), w2 = expf(mm[2] - mmx);
    float si = 1.0f / (w0 + w1 + w2);
    P[e].mixw0 = w0 * si; P[e].mixw1 = w1 * si; P[e].mixw2 = w2 * si;
    P[e].maxslot = 0u;
  }

  // argmax over 512 control-plane logits
  const float* c = cpc + (size_t)e * NCP;
  float bv = -INFINITY; int bi = 0;
  for (int i = tid; i < NCP; i += 64) {
    float x = c[i];
    if (x > bv) { bv = x; bi = i; } // i increasing -> first occurrence kept
  }
  bvals[tid] = bv; bidx[tid] = bi;
  __syncthreads();
  if (tid == 0) {
    float best = bvals[0]; int besti = bidx[0];
    for (int i = 1; i < 64; ++i) {
      if (bvals[i] > best || (bvals[i] == best && bidx[i] < besti)) { best = bvals[i]; besti = bidx[i]; }
    }
    P[e].cpidx = besti;
  }
}

// ============================== Kv: verb chunk FFTs ==============================
__global__ __launch_bounds__(256) void kv_fft(const float* __restrict__ verbs, float2* __restrict__ Vhat) {
  __shared__ float re[FFTN], im[FFTN], twr[FFTN / 2], twi[FFTN / 2];
  int v = blockIdx.x >> 7, j = blockIdx.x & 127;
  int tid = threadIdx.x;
  fill_tw(twr, twi, tid);
  const float* src = verbs + (size_t)v * NS + j * WIN;
  for (int i = tid; i < FFTN; i += 256) {
    int r = __brev(i) >> (32 - FFT_LOG2);
    float val = (i < WIN) ? src[i] : 0.0f;
    re[r] = val; im[r] = 0.0f;
  }
  __syncthreads();
  fft_stages(re, im, twr, twi, tid, false);
  float2* dst = Vhat + ((size_t)v * NFR + j) * NBINS;
  for (int k = tid; k < NBINS; k += 256) dst[k] = make_float2(re[k], im[k]);
}

// ============================== K1a: recurrent synthesis ==============================
__global__ __launch_bounds__(256) void k1a_synth(const float* __restrict__ cp_items,
                                                 const float* __restrict__ w1_all,
                                                 const float* __restrict__ w2_all,
                                                 const float* __restrict__ decays,
                                                 const float* __restrict__ gains,
                                                 const EvParams* __restrict__ P,
                                                 float* __restrict__ cp_out_all) {
  __shared__ float cpv[2048];
  __shared__ float wc[2048], xb[2048], yb[2048];
  __shared__ float w1s[256], w2s[256];
  __shared__ float dv[16], gv[16];
  __shared__ float rv[256];
  __shared__ int ri[256];
  __shared__ float s_scale;

  int e = blockIdx.x, tid = threadIdx.x;
  int vidx = P[e].vidx, cpidx = P[e].cpidx;

  // load cp + sum
  float ls = 0.0f;
  for (int i = tid; i < 2048; i += 256) {
    float x = cp_items[(size_t)cpidx * 2048 + i];
    cpv[i] = x;
    ls += x;
  }
  rv[tid] = ls;
  __syncthreads();
  for (int s = 128; s > 0; s >>= 1) { if (tid < s) rv[tid] += rv[tid + s]; __syncthreads(); }
  if (tid == 0) s_scale = 1.0f / (rv[0] + 1e-8f);
  for (int i = tid; i < 2048; i += 256) wc[i] = 0.0f;
  __syncthreads();
  float scale = s_scale;

  // top-32 (first-index tiebreak, matching lax.top_k stability)
  for (int it = 0; it < 32; ++it) {
    float bv = -1.0f; int bi = 1 << 30;
    for (int i = tid; i < 2048; i += 256) {
      float x = cpv[i];
      if (x > bv) { bv = x; bi = i; }
    }
    rv[tid] = bv; ri[tid] = bi;
    __syncthreads();
    for (int s = 128; s > 0; s >>= 1) {
      if (tid < s) {
        float ov = rv[tid + s]; int oi = ri[tid + s];
        if (ov > rv[tid] || (ov == rv[tid] && oi < ri[tid])) { rv[tid] = ov; ri[tid] = oi; }
      }
      __syncthreads();
    }
    if (tid == 0) { int mi = ri[0]; wc[mi] = cpv[mi] * scale; cpv[mi] = -2.0f; }
    __syncthreads();
  }

  // 3 recurrent layers
  for (int l = 0; l < NBLK; ++l) {
    int wbase = (vidx * NBLK + l) * 256;
    w1s[tid] = w1_all[wbase + tid];
    w2s[tid] = w2_all[wbase + tid];
    if (tid < 16) {
      float dp = decays[(vidx * NBLK + l) * 16 + tid];
      float sd = 1.0f / (1.0f + expf(-dp));
      dv[tid] = 1e-12f + 0.5f + 0.5f * sd;
      float gp = gains[(vidx * NBLK + l) * 16 + tid];
      gv[tid] = 5.0f / (1.0f + expf(-gp));
    }
    __syncthreads();
    // x = w1 @ relu(wc)
    for (int i = tid; i < 2048; i += 256) {
      int cch = i >> 7, f = i & 127;
      float acc = 0.0f;
      #pragma unroll
      for (int k = 0; k < 16; ++k) acc += w1s[cch * 16 + k] * fmaxf(wc[k * 128 + f], 0.0f);
      xb[i] = acc;
    }
    __syncthreads();
    // IIR: y[t] = m*(y[t-1] + x[t])  == conv with env m^(u+1)
    if (tid < 16) {
      float a = 0.0f, d = dv[tid];
      for (int t = 0; t < 128; ++t) { a = d * (a + xb[tid * 128 + t]); yb[tid * 128 + t] = a; }
    }
    __syncthreads();
    // x2 = w2 @ y + orig; cp_out = tanh(x2 * g)
    for (int i = tid; i < 2048; i += 256) {
      int cch = i >> 7, f = i & 127;
      float acc = xb[i];
      #pragma unroll
      for (int k = 0; k < 16; ++k) acc += w2s[cch * 16 + k] * yb[k * 128 + f];
      float co = tanhf(acc * gv[cch]);
      wc[i] = co;
      cp_out_all[((size_t)e * NBLK + l) * 2048 + i] = co;
    }
    __syncthreads();
  }
}

// ============================== K1b: audio matmul + mix + maxabs ==============================
__global__ __launch_bounds__(256) void k1b_audio(const float* __restrict__ amaps,
                                                 const float* __restrict__ cp_out_all,
                                                 EvParams* __restrict__ P,
                                                 float* __restrict__ mixed) {
  __shared__ float cps[NBLK][16][16]; // [bl][c][fl]
  __shared__ float red[256];
  int e = blockIdx.x >> 3, fg = blockIdx.x & 7;
  int f0 = fg * 16, tid = threadIdx.x;
  int vidx = P[e].vidx;
  float mw[3] = {P[e].mixw0, P[e].mixw1, P[e].mixw2};

  for (int i = tid; i < NBLK * 256; i += 256) {
    int bl = i >> 8, r = i & 255, cch = r >> 4, fl = r & 15;
    cps[bl][cch][fl] = cp_out_all[((size_t)e * NBLK + bl) * 2048 + cch * 128 + f0 + fl];
  }
  __syncthreads();

  float amax = 0.0f;
  for (int jw = 0; jw < 4; ++jw) {
    int w = jw * 256 + tid;
    float am[NBLK][16];
    #pragma unroll
    for (int bl = 0; bl < NBLK; ++bl) {
      const float* ap = amaps + (((size_t)(vidx * NBLK + bl)) * WIN + w) * CPDIM;
      #pragma unroll
      for (int cch = 0; cch < 16; ++cch) am[bl][cch] = ap[cch] * mw[bl];
    }
    for (int fl = 0; fl < 16; ++fl) {
      float acc = 0.0f;
      #pragma unroll
      for (int bl = 0; bl < NBLK; ++bl)
        #pragma unroll
        for (int cch = 0; cch < 16; ++cch) acc += am[bl][cch] * cps[bl][cch][fl];
      mixed[(size_t)e * NS + (size_t)(f0 + fl) * WIN + w] = acc;
      amax = fmaxf(amax, fabsf(acc));
    }
  }
  red[tid] = amax;
  __syncthreads();
  for (int s = 128; s > 0; s >>= 1) { if (tid < s) red[tid] = fmaxf(red[tid], red[tid + s]); __syncthreads(); }
  if (tid == 0) atomicMax(&P[e].maxslot, __float_as_uint(red[0]));
}

// ============================== K2: forward chunk FFTs (scaled by 1/(max+1e-8)) ==============================
__global__ __launch_bounds__(256) void k2_fwd_fft(const float* __restrict__ mixed,
                                                  const EvParams* __restrict__ P,
                                                  float2* __restrict__ Shat) {
  __shared__ float re[FFTN], im[FFTN], twr[FFTN / 2], twi[FFTN / 2];
  int e = blockIdx.x >> 7, p = blockIdx.x & 127;
  int tid = threadIdx.x;
  float invn = 1.0f / (__uint_as_float(P[e].maxslot) + 1e-8f);
  fill_tw(twr, twi, tid);
  const float* src = mixed + (size_t)e * NS + p * WIN;
  for (int i = tid; i < FFTN; i += 256) {
    int r = __brev(i) >> (32 - FFT_LOG2);
    float val = (i < WIN) ? src[i] * invn : 0.0f;
    re[r] = val; im[r] = 0.0f;
  }
  __syncthreads();
  fft_stages(re, im, twr, twi, tid, false);
  float2* dst = Shat + ((size_t)e * NFR + p) * NBINS;
  for (int k = tid; k < NBINS; k += 256) dst[k] = make_float2(re[k], im[k]);
}

// ============================== K3: double triangular conv in chunk-frequency domain ==============================
__global__ __launch_bounds__(256) void k3_conv(const float2* __restrict__ Shat,
                                               const float2* __restrict__ Vhat,
                                               const float* __restrict__ times_g,
                                               const EvParams* __restrict__ P,
                                               float2* __restrict__ Ohat) {
  __shared__ float Sre[128 * 32], Sim[128 * 32];
  __shared__ float Vre[128 * 32], Vim[128 * 32]; // reused as U after first conv
  __shared__ float tms[128];

  int bx = blockIdx.x;
  int e = bx / 33, bg = bx % 33;
  int bin0 = bg * 32;
  int tid = threadIdx.x;
  int b = tid & 31, pg = tid >> 5;
  int p0 = pg * 16;

  int ridx = P[e].ridx;
  float vm0 = P[e].vm0, vm1 = P[e].vm1, amp = P[e].amp;

  const float2* Sg = Shat + (size_t)e * NFR * NBINS;
  const float2* Vg = Vhat + (size_t)ridx * NFR * NBINS;
  for (int i = tid; i < 128 * 32; i += 256) {
    int f = i >> 5, bb = i & 31;
    int bin = bin0 + bb; if (bin > 1024) bin = 1024;
    float2 s = Sg[f * NBINS + bin];
    Sre[i] = s.x; Sim[i] = s.y;
    float2 v = Vg[f * NBINS + bin];
    Vre[i] = v.x; Vim[i] = v.y;
  }
  if (tid < 128) tms[tid] = times_g[e * NFR + tid];
  __syncthreads();

  // -------- first conv: G_p = sum_{f=0..p} S_f * V_{p-f}, p in [p0, p0+16) --------
  float ar[16], ai[16];
  #pragma unroll
  for (int t = 0; t < 16; ++t) { ar[t] = 0.0f; ai[t] = 0.0f; }

  for (int ft = 0; ft < pg; ++ft) {
    int f0v = ft * 16;
    float sr[16], si[16];
    #pragma unroll
    for (int ff = 0; ff < 16; ++ff) { int f = f0v + ff; sr[ff] = Sre[f * 32 + b]; si[ff] = Sim[f * 32 + b]; }
    float vr[31], vi[31];
    int jb = p0 - f0v - 15;
    #pragma unroll
    for (int m = 0; m < 31; ++m) { int j = jb + m; vr[m] = Vre[j * 32 + b]; vi[m] = Vim[j * 32 + b]; }
    #pragma unroll
    for (int ff = 0; ff < 16; ++ff) {
      #pragma unroll
      for (int t = 0; t < 16; ++t) {
        int m = 15 - ff + t;
        ar[t] += sr[ff] * vr[m] - si[ff] * vi[m];
        ai[t] += sr[ff] * vi[m] + si[ff] * vr[m];
      }
    }
  }
  { // diagonal tile f in [p0, p0+15], constraint f <= p
    float sr[16], si[16];
    #pragma unroll
    for (int ff = 0; ff < 16; ++ff) { int f = p0 + ff; sr[ff] = Sre[f * 32 + b]; si[ff] = Sim[f * 32 + b]; }
    float vr[16], vi[16];
    #pragma unroll
    for (int m = 0; m < 16; ++m) { vr[m] = Vre[m * 32 + b]; vi[m] = Vim[m * 32 + b]; }
    #pragma unroll
    for (int ff = 0; ff < 16; ++ff) {
      #pragma unroll
      for (int t = 0; t < 16; ++t) {
        if (t >= ff) {
          int m = t - ff;
          ar[t] += sr[ff] * vr[m] - si[ff] * vi[m];
          ai[t] += sr[ff] * vi[m] + si[ff] * vr[m];
        }
      }
    }
  }

  // -------- U_p = amp*(vm0*G_p + vm1*S_p); store into V's LDS --------
  __syncthreads();
  #pragma unroll
  for (int t = 0; t < 16; ++t) {
    int p = p0 + t;
    float sre = Sre[p * 32 + b], sim = Sim[p * 32 + b];
    Vre[p * 32 + b] = amp * (vm0 * ar[t] + vm1 * sre);
    Vim[p * 32 + b] = amp * (vm0 * ai[t] + vm1 * sim);
  }
  __syncthreads();

  // -------- second conv: O_p = sum_{r=0..p} times[r] * U_{p-r} --------
  #pragma unroll
  for (int t = 0; t < 16; ++t) { ar[t] = 0.0f; ai[t] = 0.0f; }

  for (int ft = 0; ft < pg; ++ft) {
    int f0v = ft * 16;
    float trr[16];
    #pragma unroll
    for (int ff = 0; ff < 16; ++ff) trr[ff] = tms[f0v + ff];
    float ur[31], ui[31];
    int jb = p0 - f0v - 15;
    #pragma unroll
    for (int m = 0; m < 31; ++m) { int j = jb + m; ur[m] = Vre[j * 32 + b]; ui[m] = Vim[j * 32 + b]; }
    #pragma unroll
    for (int ff = 0; ff < 16; ++ff) {
      #pragma unroll
      for (int t = 0; t < 16; ++t) {
        int m = 15 - ff + t;
        ar[t] += trr[ff] * ur[m];
        ai[t] += trr[ff] * ui[m];
      }
    }
  }
  { // diagonal
    float trr[16];
    #pragma unroll
    for (int ff = 0; ff < 16; ++ff) trr[ff] = tms[p0 + ff];
    float ur[16], ui[16];
    #pragma unroll
    for (int m = 0; m < 16; ++m) { ur[m] = Vre[m * 32 + b]; ui[m] = Vim[m * 32 + b]; }
    #pragma unroll
    for (int ff = 0; ff < 16; ++ff) {
      #pragma unroll
      for (int t = 0; t < 16; ++t) {
        if (t >= ff) {
          int m = t - ff;
          ar[t] += trr[ff] * ur[m];
          ai[t] += trr[ff] * ui[m];
        }
      }
    }
  }

  if (bin0 + b <= 1024) {
    float2* Og = Ohat + (size_t)e * NFR * NBINS;
    #pragma unroll
    for (int t = 0; t < 16; ++t) {
      Og[(p0 + t) * NBINS + bin0 + b] = make_float2(ar[t], ai[t]);
    }
  }
}

// ============================== K4: inverse chunk FFTs + write halves ==============================
__global__ __launch_bounds__(256) void k4_ifft(const float2* __restrict__ Ohat,
                                               float* __restrict__ out,
                                               float* __restrict__ tail) {
  __shared__ float re[FFTN], im[FFTN], twr[FFTN / 2], twi[FFTN / 2];
  int e = blockIdx.x >> 7, p = blockIdx.x & 127;
  int tid = threadIdx.x;
  fill_tw(twr, twi, tid);
  const float2* src = Ohat + ((size_t)e * NFR + p) * NBINS;
  for (int i = tid; i < FFTN; i += 256) {
    float xr, xi;
    if (i <= 1024) { float2 v = src[i]; xr = v.x; xi = v.y; }
    else           { float2 v = src[FFTN - i]; xr = v.x; xi = -v.y; }
    int r = __brev(i) >> (32 - FFT_LOG2);
    re[r] = xr; im[r] = xi;
  }
  __syncthreads();
  fft_stages(re, im, twr, twi, tid, true);
  const float inv = 1.0f / (float)FFTN;
  float* o = out + (size_t)e * NS + p * WIN;
  for (int u = tid; u < WIN; u += 256) o[u] = re[u] * inv;
  float* t = tail + ((size_t)e * NFR + p) * WIN;
  for (int u = tid; u < WIN; u += 256) t[u] = re[WIN + u] * inv;
}

// ============================== K5: overlap-add tails ==============================
__global__ __launch_bounds__(256) void k5_tail(const float* __restrict__ tail, float* __restrict__ out) {
  size_t idx = (size_t)blockIdx.x * 256 + threadIdx.x;
  if (idx >= (size_t)NEV * 127 * WIN) return;
  int u = (int)(idx & 1023);
  size_t rest = idx >> 10;
  int pm1 = (int)(rest % 127);
  int e = (int)(rest / 127);
  int p = pm1 + 1;
  out[(size_t)e * NS + (size_t)p * WIN + u] += tail[((size_t)e * NFR + pm1) * WIN + u];
}

// ============================== launch ==============================
extern "C" void kernel_launch(void* const* d_in, const int* in_sizes, int n_in,
                              void* d_out, int out_size, void* d_ws, size_t ws_size,
                              hipStream_t stream) {
  (void)in_sizes; (void)n_in; (void)out_size; (void)ws_size;
  const float* voice    = (const float*)d_in[0];
  const float* cpc      = (const float*)d_in[1];
  const float* amps     = (const float*)d_in[2];
  const float* roomc    = (const float*)d_in[3];
  const float* roomm    = (const float*)d_in[4];
  const float* times    = (const float*)d_in[5];
  const float* cp_items = (const float*)d_in[6];
  const float* verbs    = (const float*)d_in[7];
  const float* w1       = (const float*)d_in[8];
  const float* w2       = (const float*)d_in[9];
  const float* amaps    = (const float*)d_in[10];
  const float* decays   = (const float*)d_in[11];
  const float* gains    = (const float*)d_in[12];
  const float* mix      = (const float*)d_in[13];
  float* out = (float*)d_out;

  // workspace layout (bytes):
  //   P:          [0, 4096)
  //   cp_out_all: 393216 f32
  //   mixed:      8388608 f32          (aliased as `tail` after K2 is done)
  //   Shat:       8396800 float2       (aliased as Ohat; K3 rewrites only bins it loaded)
  //   Vhat:       1049600 float2
  char* base = (char*)d_ws;
  EvParams* P       = (EvParams*)base;
  float* cp_out_all = (float*)(base + 4096);
  float* mixed      = (float*)(base + 4096 + (size_t)393216 * 4);
  float2* Shat      = (float2*)(base + 4096 + ((size_t)393216 + 8388608) * 4);
  float2* Vhat      = (float2*)((char*)Shat + (size_t)8396800 * 8);
  float* tail  = mixed;  // safe: mixed last read in K2; tail first written in K4
  float2* Ohat = Shat;   // safe: each K3 block loads its bins to LDS before overwriting them

  k0_params<<<NEV, 64, 0, stream>>>(voice, cpc, amps, roomc, roomm, mix, P);
  kv_fft<<<NVERB * NFR, 256, 0, stream>>>(verbs, Vhat);
  k1a_synth<<<NEV, 256, 0, stream>>>(cp_items, w1, w2, decays, gains, P, cp_out_all);
  k1b_audio<<<NEV * 8, 256, 0, stream>>>(amaps, cp_out_all, P, mixed);
  k2_fwd_fft<<<NEV * NFR, 256, 0, stream>>>(mixed, P, Shat);
  k3_conv<<<NEV * 33, 256, 0, stream>>>(Shat, Vhat, times, P, Ohat);
  k4_ifft<<<NEV * NFR, 256, 0, stream>>>(Ohat, out, tail);
  k5_tail<<<(NEV * 127 * WIN) / 256, 256, 0, stream>>>(tail, out);
}

// Round 2
// 558.580 us; speedup vs baseline: 1.6514x; 1.6514x over previous
//
#include <hip/hip_runtime.h>
#include <math.h>

#define NS 131072
#define NFR 128
#define CPDIM 16
#define WIN 1024
#define NVOICE 8
#define NBLK 3
#define NCP 512
#define NVERB 8
#define NEV 64
#define N1 1024          // complex FFT length (real length 2048)
#define NBINS 1025

struct EvParams {
  int vidx, cpidx, ridx;
  float vm0, vm1, amp;
  float mixw0, mixw1, mixw2;
  unsigned int maxslot;
  int pad[6];
}; // 64 bytes

// ============================== K_tw: twiddle table e^{-2pi i k/2048}, k=0..1023 ==============================
__global__ void kt_tw(float2* __restrict__ tw) {
  int k = blockIdx.x * 256 + threadIdx.x;
  if (k < 1024) {
    float ang = -3.067961575771282340e-03f * (float)k; // -2pi/2048
    float s, c;
    sincosf(ang, &s, &c);
    tw[k] = make_float2(c, s);
  }
}

// ============================== FFT-1024 stages (in-place, bit-reversed input) ==============================
// twl: LDS copy of the 1024-entry 2048-base table; stage-s twiddle = twl[j << (11-s)]
__device__ __forceinline__ void fft1024(float* re, float* im, const float2* twl,
                                        int tid, bool inverse) {
  #pragma unroll
  for (int s = 1; s <= 10; ++s) {
    const int half = 1 << (s - 1);
    const int tsh = 11 - s;
    for (int k = tid; k < 512; k += 256) {
      int j = k & (half - 1);
      int i0 = ((k ^ j) << 1) | j;
      int i1 = i0 + half;
      float2 w = twl[j << tsh];
      float wr = w.x, wi = inverse ? -w.y : w.y;
      float xr = re[i1], xi = im[i1];
      float tr = wr * xr - wi * xi;
      float ti = wr * xi + wi * xr;
      float ur = re[i0], ui = im[i0];
      re[i0] = ur + tr; im[i0] = ui + ti;
      re[i1] = ur - tr; im[i1] = ui - ti;
    }
    __syncthreads();
  }
}

// real-2048 forward FFT via packed complex-1024; src2 = 512 float2 (1024 reals), rest zero
__device__ __forceinline__ void rfft_fwd(const float2* __restrict__ src2, float scale,
                                         float2* __restrict__ dst,
                                         float* re, float* im, float2* twl,
                                         const float2* __restrict__ twg, int tid) {
  for (int i = tid; i < 1024; i += 256) twl[i] = twg[i];
  for (int n = tid; n < 1024; n += 256) {
    int r = __brev(n) >> 22;
    if (n < 512) {
      float2 x = src2[n];
      re[r] = x.x * scale; im[r] = x.y * scale;
    } else { re[r] = 0.0f; im[r] = 0.0f; }
  }
  __syncthreads();
  fft1024(re, im, twl, tid, false);
  // untwist: X[k] = A + W_k B, W_k = e^{-i pi k/1024} = twl[k]
  for (int k = tid; k <= 1024; k += 256) {
    int km = (1024 - k) & 1023;
    float zr = re[k & 1023], zi = im[k & 1023];
    float mr = re[km], mi = im[km];
    float Are = 0.5f * (zr + mr), Aim = 0.5f * (zi - mi);
    float Bre = 0.5f * (zi + mi), Bim = 0.5f * (mr - zr);
    float wr, wi;
    if (k == 1024) { wr = -1.0f; wi = 0.0f; }
    else { float2 w = twl[k]; wr = w.x; wi = w.y; }
    dst[k] = make_float2(Are + wr * Bre - wi * Bim, Aim + wr * Bim + wi * Bre);
  }
}

// ============================== K0: per-event params ==============================
__global__ void k0_params(const float* __restrict__ voice, const float* __restrict__ cpc,
                          const float* __restrict__ amps, const float* __restrict__ roomc,
                          const float* __restrict__ roomm, const float* __restrict__ mix,
                          EvParams* __restrict__ P) {
  int e = blockIdx.x;
  int tid = threadIdx.x; // 64 threads
  __shared__ float bvals[64];
  __shared__ int bidx[64];

  if (tid == 0) {
    const float* v = voice + e * NVOICE;
    int vi = 0; float bv = v[0];
    for (int i = 1; i < NVOICE; ++i) if (v[i] > bv) { bv = v[i]; vi = i; }
    P[e].vidx = vi;

    const float* r = roomc + e * NVERB;
    int ri = 0; float br = r[0];
    for (int i = 1; i < NVERB; ++i) if (r[i] > br) { br = r[i]; ri = i; }
    P[e].ridx = ri;

    float m0 = roomm[e * 2 + 0], m1 = roomm[e * 2 + 1];
    float mx = fmaxf(m0, m1);
    float e0 = expf(m0 - mx), e1 = expf(m1 - mx);
    float inv = 1.0f / (e0 + e1);
    P[e].vm0 = e0 * inv;
    P[e].vm1 = e1 * inv;
    P[e].amp = fabsf(amps[e]);

    const float* mm = mix + vi * NBLK;
    float mmx = fmaxf(fmaxf(mm[0], mm[1]), mm[2]);
    float w0 = expf(mm[0] - mmx), w1 = expf(mm[1] - mmx), w2 = expf(mm[2] - mmx);
    float si = 1.0f / (w0 + w1 + w2);
    P[e].mixw0 = w0 * si; P[e].mixw1 = w1 * si; P[e].mixw2 = w2 * si;
    P[e].maxslot = 0u;
  }

  const float* c = cpc + (size_t)e * NCP;
  float bv = -INFINITY; int bi = 0;
  for (int i = tid; i < NCP; i += 64) {
    float x = c[i];
    if (x > bv) { bv = x; bi = i; }
  }
  bvals[tid] = bv; bidx[tid] = bi;
  __syncthreads();
  if (tid == 0) {
    float best = bvals[0]; int besti = bidx[0];
    for (int i = 1; i < 64; ++i) {
      if (bvals[i] > best || (bvals[i] == best && bidx[i] < besti)) { best = bvals[i]; besti = bidx[i]; }
    }
    P[e].cpidx = besti;
  }
}

// ============================== Kv: verb chunk FFTs ==============================
__global__ __launch_bounds__(256) void kv_fft(const float* __restrict__ verbs,
                                              const float2* __restrict__ twg,
                                              float2* __restrict__ Vhat) {
  __shared__ float re[N1], im[N1];
  __shared__ float2 twl[N1];
  int v = blockIdx.x >> 7, j = blockIdx.x & 127;
  int tid = threadIdx.x;
  rfft_fwd((const float2*)(verbs + (size_t)v * NS + j * WIN), 1.0f,
           Vhat + ((size_t)v * NFR + j) * NBINS, re, im, twl, twg, tid);
}

// ============================== K1a: recurrent synthesis ==============================
__global__ __launch_bounds__(256) void k1a_synth(const float* __restrict__ cp_items,
                                                 const float* __restrict__ w1_all,
                                                 const float* __restrict__ w2_all,
                                                 const float* __restrict__ decays,
                                                 const float* __restrict__ gains,
                                                 const EvParams* __restrict__ P,
                                                 float* __restrict__ cp_out_all) {
  __shared__ float cpv[2048];
  __shared__ float wc[2048], xb[2048], yb[2048];
  __shared__ float w1s[256], w2s[256];
  __shared__ float dv[16], gv[16];
  __shared__ float rv[256];
  __shared__ int ri[256];
  __shared__ float s_scale;

  int e = blockIdx.x, tid = threadIdx.x;
  int vidx = P[e].vidx, cpidx = P[e].cpidx;

  float ls = 0.0f;
  for (int i = tid; i < 2048; i += 256) {
    float x = cp_items[(size_t)cpidx * 2048 + i];
    cpv[i] = x;
    ls += x;
  }
  rv[tid] = ls;
  __syncthreads();
  for (int s = 128; s > 0; s >>= 1) { if (tid < s) rv[tid] += rv[tid + s]; __syncthreads(); }
  if (tid == 0) s_scale = 1.0f / (rv[0] + 1e-8f);
  for (int i = tid; i < 2048; i += 256) wc[i] = 0.0f;
  __syncthreads();
  float scale = s_scale;

  for (int it = 0; it < 32; ++it) {
    float bv = -1.0f; int bi = 1 << 30;
    for (int i = tid; i < 2048; i += 256) {
      float x = cpv[i];
      if (x > bv) { bv = x; bi = i; }
    }
    rv[tid] = bv; ri[tid] = bi;
    __syncthreads();
    for (int s = 128; s > 0; s >>= 1) {
      if (tid < s) {
        float ov = rv[tid + s]; int oi = ri[tid + s];
        if (ov > rv[tid] || (ov == rv[tid] && oi < ri[tid])) { rv[tid] = ov; ri[tid] = oi; }
      }
      __syncthreads();
    }
    if (tid == 0) { int mi = ri[0]; wc[mi] = cpv[mi] * scale; cpv[mi] = -2.0f; }
    __syncthreads();
  }

  for (int l = 0; l < NBLK; ++l) {
    int wbase = (vidx * NBLK + l) * 256;
    w1s[tid] = w1_all[wbase + tid];
    w2s[tid] = w2_all[wbase + tid];
    if (tid < 16) {
      float dp = decays[(vidx * NBLK + l) * 16 + tid];
      float sd = 1.0f / (1.0f + expf(-dp));
      dv[tid] = 1e-12f + 0.5f + 0.5f * sd;
      float gp = gains[(vidx * NBLK + l) * 16 + tid];
      gv[tid] = 5.0f / (1.0f + expf(-gp));
    }
    __syncthreads();
    for (int i = tid; i < 2048; i += 256) {
      int cch = i >> 7, f = i & 127;
      float acc = 0.0f;
      #pragma unroll
      for (int k = 0; k < 16; ++k) acc += w1s[cch * 16 + k] * fmaxf(wc[k * 128 + f], 0.0f);
      xb[i] = acc;
    }
    __syncthreads();
    if (tid < 16) {
      float a = 0.0f, d = dv[tid];
      for (int t = 0; t < 128; ++t) { a = d * (a + xb[tid * 128 + t]); yb[tid * 128 + t] = a; }
    }
    __syncthreads();
    for (int i = tid; i < 2048; i += 256) {
      int cch = i >> 7, f = i & 127;
      float acc = xb[i];
      #pragma unroll
      for (int k = 0; k < 16; ++k) acc += w2s[cch * 16 + k] * yb[k * 128 + f];
      float co = tanhf(acc * gv[cch]);
      wc[i] = co;
      cp_out_all[((size_t)e * NBLK + l) * 2048 + i] = co;
    }
    __syncthreads();
  }
}

// ============================== K1b: audio matmul + mix + maxabs ==============================
__global__ __launch_bounds__(256) void k1b_audio(const float* __restrict__ amaps,
                                                 const float* __restrict__ cp_out_all,
                                                 EvParams* __restrict__ P,
                                                 float* __restrict__ mixed) {
  __shared__ float cps[NBLK][16][16]; // [bl][c][fl]
  __shared__ float red[256];
  int e = blockIdx.x >> 3, fg = blockIdx.x & 7;
  int f0 = fg * 16, tid = threadIdx.x;
  int vidx = P[e].vidx;
  float mw[3] = {P[e].mixw0, P[e].mixw1, P[e].mixw2};

  for (int i = tid; i < NBLK * 256; i += 256) {
    int bl = i >> 8, r = i & 255, cch = r >> 4, fl = r & 15;
    cps[bl][cch][fl] = cp_out_all[((size_t)e * NBLK + bl) * 2048 + cch * 128 + f0 + fl];
  }
  __syncthreads();

  float amax = 0.0f;
  for (int jw = 0; jw < 4; ++jw) {
    int w = jw * 256 + tid;
    float am[NBLK][16];
    #pragma unroll
    for (int bl = 0; bl < NBLK; ++bl) {
      const float* ap = amaps + (((size_t)(vidx * NBLK + bl)) * WIN + w) * CPDIM;
      #pragma unroll
      for (int cch = 0; cch < 16; ++cch) am[bl][cch] = ap[cch] * mw[bl];
    }
    for (int fl = 0; fl < 16; ++fl) {
      float acc = 0.0f;
      #pragma unroll
      for (int bl = 0; bl < NBLK; ++bl)
        #pragma unroll
        for (int cch = 0; cch < 16; ++cch) acc += am[bl][cch] * cps[bl][cch][fl];
      mixed[(size_t)e * NS + (size_t)(f0 + fl) * WIN + w] = acc;
      amax = fmaxf(amax, fabsf(acc));
    }
  }
  red[tid] = amax;
  __syncthreads();
  for (int s = 128; s > 0; s >>= 1) { if (tid < s) red[tid] = fmaxf(red[tid], red[tid + s]); __syncthreads(); }
  if (tid == 0) atomicMax(&P[e].maxslot, __float_as_uint(red[0]));
}

// ============================== K2: forward chunk FFTs (scaled by 1/(max+1e-8)) ==============================
__global__ __launch_bounds__(256) void k2_fwd(const float* __restrict__ mixed,
                                              const EvParams* __restrict__ P,
                                              const float2* __restrict__ twg,
                                              float2* __restrict__ Shat) {
  __shared__ float re[N1], im[N1];
  __shared__ float2 twl[N1];
  int e = blockIdx.x >> 7, p = blockIdx.x & 127;
  int tid = threadIdx.x;
  float invn = 1.0f / (__uint_as_float(P[e].maxslot) + 1e-8f);
  rfft_fwd((const float2*)(mixed + (size_t)e * NS + p * WIN), invn,
           Shat + ((size_t)e * NFR + p) * NBINS, re, im, twl, twg, tid);
}

// ============================== K3: double triangular conv in chunk-frequency domain ==============================
// 16 bins/block, 16 p-octs of 8; LDS 33 KB -> 4 blocks/CU
__global__ __launch_bounds__(256, 4) void k3_conv(const float2* __restrict__ Shat,
                                                  const float2* __restrict__ Vhat,
                                                  const float* __restrict__ times_g,
                                                  const EvParams* __restrict__ P,
                                                  float2* __restrict__ Ohat) {
  __shared__ float Sre[128 * 16], Sim[128 * 16];
  __shared__ float Vre[128 * 16], Vim[128 * 16]; // reused as U after first conv
  __shared__ float tms[128];

  int bx = blockIdx.x;
  int e = bx / 65, bg = bx % 65;
  int bin0 = bg * 16;
  int tid = threadIdx.x;
  int b = tid & 15, pg = tid >> 4;
  int p0 = pg * 8;

  int ridx = P[e].ridx;
  float vm0 = P[e].vm0, vm1 = P[e].vm1, amp = P[e].amp;

  const float2* Sg = Shat + (size_t)e * NFR * NBINS;
  const float2* Vg = Vhat + (size_t)ridx * NFR * NBINS;
  for (int i = tid; i < 2048; i += 256) {
    int f = i >> 4, bb = i & 15;
    int bin = bin0 + bb; if (bin > 1024) bin = 1024;
    float2 s = Sg[f * NBINS + bin];
    Sre[i] = s.x; Sim[i] = s.y;
    float2 v = Vg[f * NBINS + bin];
    Vre[i] = v.x; Vim[i] = v.y;
  }
  if (tid < 128) tms[tid] = times_g[e * NFR + tid];
  __syncthreads();

  // -------- first conv: G_p = sum_{f=0..p} S_f * V_{p-f}, p in [p0, p0+8) --------
  float ar[8], ai[8];
  #pragma unroll
  for (int t = 0; t < 8; ++t) { ar[t] = 0.0f; ai[t] = 0.0f; }

  for (int ft = 0; ft < pg; ++ft) {
    int f0v = ft * 8;
    float sr[8], si[8];
    #pragma unroll
    for (int ff = 0; ff < 8; ++ff) { int f = f0v + ff; sr[ff] = Sre[f * 16 + b]; si[ff] = Sim[f * 16 + b]; }
    float vr[15], vi[15];
    int jb = p0 - f0v - 7;
    #pragma unroll
    for (int m = 0; m < 15; ++m) { int j = jb + m; vr[m] = Vre[j * 16 + b]; vi[m] = Vim[j * 16 + b]; }
    #pragma unroll
    for (int ff = 0; ff < 8; ++ff) {
      #pragma unroll
      for (int t = 0; t < 8; ++t) {
        int m = 7 - ff + t;
        ar[t] += sr[ff] * vr[m] - si[ff] * vi[m];
        ai[t] += sr[ff] * vi[m] + si[ff] * vr[m];
      }
    }
  }
  { // diagonal tile f in [p0, p0+7], constraint f <= p
    float sr[8], si[8];
    #pragma unroll
    for (int ff = 0; ff < 8; ++ff) { int f = p0 + ff; sr[ff] = Sre[f * 16 + b]; si[ff] = Sim[f * 16 + b]; }
    float vr[8], vi[8];
    #pragma unroll
    for (int m = 0; m < 8; ++m) { vr[m] = Vre[m * 16 + b]; vi[m] = Vim[m * 16 + b]; }
    #pragma unroll
    for (int ff = 0; ff < 8; ++ff) {
      #pragma unroll
      for (int t = 0; t < 8; ++t) {
        if (t >= ff) {
          int m = t - ff;
          ar[t] += sr[ff] * vr[m] - si[ff] * vi[m];
          ai[t] += sr[ff] * vi[m] + si[ff] * vr[m];
        }
      }
    }
  }

  // -------- U_p = amp*(vm0*G_p + vm1*S_p); store into V's LDS --------
  __syncthreads();
  #pragma unroll
  for (int t = 0; t < 8; ++t) {
    int p = p0 + t;
    float sre = Sre[p * 16 + b], sim = Sim[p * 16 + b];
    Vre[p * 16 + b] = amp * (vm0 * ar[t] + vm1 * sre);
    Vim[p * 16 + b] = amp * (vm0 * ai[t] + vm1 * sim);
  }
  __syncthreads();

  // -------- second conv: O_p = sum_{r=0..p} times[r] * U_{p-r} --------
  #pragma unroll
  for (int t = 0; t < 8; ++t) { ar[t] = 0.0f; ai[t] = 0.0f; }

  for (int ft = 0; ft < pg; ++ft) {
    int f0v = ft * 8;
    float trr[8];
    #pragma unroll
    for (int ff = 0; ff < 8; ++ff) trr[ff] = tms[f0v + ff];
    float ur[15], ui[15];
    int jb = p0 - f0v - 7;
    #pragma unroll
    for (int m = 0; m < 15; ++m) { int j = jb + m; ur[m] = Vre[j * 16 + b]; ui[m] = Vim[j * 16 + b]; }
    #pragma unroll
    for (int ff = 0; ff < 8; ++ff) {
      #pragma unroll
      for (int t = 0; t < 8; ++t) {
        int m = 7 - ff + t;
        ar[t] += trr[ff] * ur[m];
        ai[t] += trr[ff] * ui[m];
      }
    }
  }
  { // diagonal
    float trr[8];
    #pragma unroll
    for (int ff = 0; ff < 8; ++ff) trr[ff] = tms[p0 + ff];
    float ur[8], ui[8];
    #pragma unroll
    for (int m = 0; m < 8; ++m) { ur[m] = Vre[m * 16 + b]; ui[m] = Vim[m * 16 + b]; }
    #pragma unroll
    for (int ff = 0; ff < 8; ++ff) {
      #pragma unroll
      for (int t = 0; t < 8; ++t) {
        if (t >= ff) {
          int m = t - ff;
          ar[t] += trr[ff] * ur[m];
          ai[t] += trr[ff] * ui[m];
        }
      }
    }
  }

  int bin = bin0 + b;
  if (bin <= 1024) {
    float2* Og = Ohat + (size_t)e * NFR * NBINS;
    #pragma unroll
    for (int t = 0; t < 8; ++t) {
      Og[(p0 + t) * NBINS + bin] = make_float2(ar[t], ai[t]);
    }
  }
}

// ============================== K4: inverse real FFT + write halves ==============================
__global__ __launch_bounds__(256) void k4_ifft(const float2* __restrict__ Ohat,
                                               const float2* __restrict__ twg,
                                               float* __restrict__ out,
                                               float* __restrict__ tail) {
  __shared__ float re[N1], im[N1];
  __shared__ float2 twl[N1];
  int e = blockIdx.x >> 7, p = blockIdx.x & 127;
  int tid = threadIdx.x;
  const float2* src = Ohat + ((size_t)e * NFR + p) * NBINS;
  for (int i = tid; i < 1024; i += 256) twl[i] = twg[i];
  __syncthreads();
  // twist: Z[k] = A + iB, A = (X_k + conj(X_{N-k}))/2, B = conj(W_k)*(X_k - conj(X_{N-k}))/2
  for (int k = tid; k < 1024; k += 256) {
    float2 Xk = src[k];
    float2 Xm = src[1024 - k];
    float Are = 0.5f * (Xk.x + Xm.x), Aim = 0.5f * (Xk.y - Xm.y);
    float Dre = 0.5f * (Xk.x - Xm.x), Dim = 0.5f * (Xk.y + Xm.y);
    float2 w = twl[k];
    float Bre = w.x * Dre + w.y * Dim;
    float Bim = w.x * Dim - w.y * Dre;
    int r = __brev(k) >> 22;
    re[r] = Are - Bim;
    im[r] = Aim + Bre;
  }
  __syncthreads();
  fft1024(re, im, twl, tid, true);
  const float inv = 1.0f / (float)N1;
  float2* o2 = (float2*)(out + (size_t)e * NS + (size_t)p * WIN);
  for (int n = tid; n < 512; n += 256) o2[n] = make_float2(re[n] * inv, im[n] * inv);
  float2* t2 = (float2*)(tail + ((size_t)e * NFR + p) * WIN);
  for (int n = tid; n < 512; n += 256) t2[n] = make_float2(re[n + 512] * inv, im[n + 512] * inv);
}

// ============================== K5: overlap-add tails ==============================
__global__ __launch_bounds__(256) void k5_tail(const float* __restrict__ tail, float* __restrict__ out) {
  size_t idx = (size_t)blockIdx.x * 256 + threadIdx.x;
  if (idx >= (size_t)NEV * 127 * WIN) return;
  int u = (int)(idx & 1023);
  size_t rest = idx >> 10;
  int pm1 = (int)(rest % 127);
  int e = (int)(rest / 127);
  int p = pm1 + 1;
  out[(size_t)e * NS + (size_t)p * WIN + u] += tail[((size_t)e * NFR + pm1) * WIN + u];
}

// ============================== launch ==============================
extern "C" void kernel_launch(void* const* d_in, const int* in_sizes, int n_in,
                              void* d_out, int out_size, void* d_ws, size_t ws_size,
                              hipStream_t stream) {
  (void)in_sizes; (void)n_in; (void)out_size; (void)ws_size;
  const float* voice    = (const float*)d_in[0];
  const float* cpc      = (const float*)d_in[1];
  const float* amps     = (const float*)d_in[2];
  const float* roomc    = (const float*)d_in[3];
  const float* roomm    = (const float*)d_in[4];
  const float* times    = (const float*)d_in[5];
  const float* cp_items = (const float*)d_in[6];
  const float* verbs    = (const float*)d_in[7];
  const float* w1       = (const float*)d_in[8];
  const float* w2       = (const float*)d_in[9];
  const float* amaps    = (const float*)d_in[10];
  const float* decays   = (const float*)d_in[11];
  const float* gains    = (const float*)d_in[12];
  const float* mix      = (const float*)d_in[13];
  float* out = (float*)d_out;

  // workspace layout (bytes):
  //   P:    4096
  //   twg:  8192 (1024 float2)
  //   cp_out_all: 393216 f32
  //   mixed: 8388608 f32     (aliased as `tail` after K2 is done)
  //   Shat: 8396800 float2   (aliased as Ohat; K3 blocks touch disjoint bins)
  //   Vhat: 1049600 float2
  char* base = (char*)d_ws;
  EvParams* P       = (EvParams*)base;
  float2* twg       = (float2*)(base + 4096);
  float* cp_out_all = (float*)(base + 4096 + 8192);
  float* mixed      = cp_out_all + (size_t)393216;
  float2* Shat      = (float2*)(mixed + (size_t)8388608);
  float2* Vhat      = Shat + (size_t)NEV * NFR * NBINS;
  float* tail  = mixed;  // safe: mixed last read in K2; tail first written in K4
  float2* Ohat = Shat;   // safe: each K3 block reads only its own bins before writing them

  kt_tw<<<4, 256, 0, stream>>>(twg);
  k0_params<<<NEV, 64, 0, stream>>>(voice, cpc, amps, roomc, roomm, mix, P);
  kv_fft<<<NVERB * NFR, 256, 0, stream>>>(verbs, twg, Vhat);
  k1a_synth<<<NEV, 256, 0, stream>>>(cp_items, w1, w2, decays, gains, P, cp_out_all);
  k1b_audio<<<NEV * 8, 256, 0, stream>>>(amaps, cp_out_all, P, mixed);
  k2_fwd<<<NEV * NFR, 256, 0, stream>>>(mixed, P, twg, Shat);
  k3_conv<<<NEV * 65, 256, 0, stream>>>(Shat, Vhat, times, P, Ohat);
  k4_ifft<<<NEV * NFR, 256, 0, stream>>>(Ohat, twg, out, tail);
  k5_tail<<<(NEV * 127 * WIN) / 256, 256, 0, stream>>>(tail, out);
}